// Round 1
// baseline (1093.709 us; speedup 1.0000x reference)
//
#include <hip/hip_runtime.h>
#include <hip/hip_bf16.h>

#define S_ 4096
#define D_ 1024
#define H_ 16
#define DK_ 64
#define F_ 4096

typedef short bf16x8_t __attribute__((ext_vector_type(8)));
typedef float f32x4_t __attribute__((ext_vector_type(4)));

__device__ __forceinline__ short bf16_rne(float f) {
  union { float f; unsigned u; } a; a.f = f;
  unsigned r = a.u + 0x7fffu + ((a.u >> 16) & 1u);
  return (short)(r >> 16);
}
__device__ __forceinline__ float bf16_to_f(short s) {
  union { unsigned u; float f; } a; a.u = ((unsigned)(unsigned short)s) << 16;
  return a.f;
}

// ---- weight prep: fp32 [K][N] (flat) or [H][K][64] (head) -> bf16 hi/lo in [N][K]
template<int HEADMODE>
__global__ __launch_bounds__(256)
void prep_w(const float* __restrict__ W, short* __restrict__ outHi,
            short* __restrict__ outLo, int K, int N) {
  __shared__ float t[32][33];
  int n0 = blockIdx.x * 32, k0 = blockIdx.y * 32;
  int tid = threadIdx.x;
  int cin = tid & 31, kin = tid >> 5;
#pragma unroll
  for (int i = 0; i < 4; ++i) {
    int k = kin + i * 8;
    int n = n0 + cin;
    long srcIdx;
    if (HEADMODE) srcIdx = ((long)(n >> 6) * K + (k0 + k)) * 64 + (n & 63);
    else          srcIdx = (long)(k0 + k) * N + n;
    t[k][cin] = W[srcIdx];
  }
  __syncthreads();
  int kout = tid & 31, cb = tid >> 5;
#pragma unroll
  for (int i = 0; i < 4; ++i) {
    int c = cb + i * 8;
    float v = t[kout][c];
    short hi = bf16_rne(v);
    short lo = bf16_rne(v - bf16_to_f(hi));
    long dst = (long)(n0 + c) * K + (k0 + kout);
    outHi[dst] = hi;
    outLo[dst] = lo;
  }
}

// ---- generic bf16x3 GEMM: C[M,N] = A(fp32,[M,K]) * B(bf16 hi/lo, [N][K]) + bias, epilogues
#define EPI_RES 1
#define EPI_RELU 2
#define EPI_QK 3
#define EPI_VT 4

template<int EPI>
__global__ __launch_bounds__(256)
void gemm128(const float* __restrict__ A, int K,
             const short* __restrict__ BtHi, const short* __restrict__ BtLo,
             const float* __restrict__ bias, const float* __restrict__ res,
             void* __restrict__ outp, int M, int N) {
  constexpr int LSTR = 40; // shorts per LDS row (80 B, 16B-aligned, breaks pow2 banks)
  __shared__ short lds[4 * 128 * LSTR];
  short* aHi = lds;
  short* aLo = lds + 128 * LSTR;
  short* bHi = lds + 2 * 128 * LSTR;
  short* bLo = lds + 3 * 128 * LSTR;

  const int m0 = blockIdx.x * 128, n0 = blockIdx.y * 128;
  const int tid = threadIdx.x;
  const int wave = tid >> 6, lane = tid & 63;
  const int wr = wave >> 1, wc = wave & 1;
  const int lg = lane >> 4, lr = lane & 15;

  float4 aReg[4];
  uint4 bRegH[2], bRegL[2];
  const int nk = K >> 5;

  // prologue: stage tile 0 into regs
#pragma unroll
  for (int p = 0; p < 4; ++p) {
    int idx = tid + p * 256;
    int row = idx >> 3, ch = idx & 7;
    aReg[p] = *(const float4*)(A + (long)(m0 + row) * K + ch * 4);
  }
#pragma unroll
  for (int p = 0; p < 2; ++p) {
    int idx = tid + p * 256;
    int row = idx >> 2, ch = idx & 3;
    long off = (long)(n0 + row) * K + ch * 8;
    bRegH[p] = *(const uint4*)(BtHi + off);
    bRegL[p] = *(const uint4*)(BtLo + off);
  }

  f32x4_t acc[4][4];
#pragma unroll
  for (int i = 0; i < 4; ++i)
#pragma unroll
    for (int j = 0; j < 4; ++j)
      acc[i][j] = (f32x4_t){0.f, 0.f, 0.f, 0.f};

  for (int kt = 0; kt < nk; ++kt) {
    if (kt) __syncthreads();
    // regs -> LDS (convert A to hi/lo)
#pragma unroll
    for (int p = 0; p < 4; ++p) {
      int idx = tid + p * 256;
      int row = idx >> 3, ch = idx & 7;
      float vv[4] = {aReg[p].x, aReg[p].y, aReg[p].z, aReg[p].w};
      short h[4], l[4];
#pragma unroll
      for (int j = 0; j < 4; ++j) {
        h[j] = bf16_rne(vv[j]);
        l[j] = bf16_rne(vv[j] - bf16_to_f(h[j]));
      }
      *(short4*)(aHi + row * LSTR + ch * 4) = make_short4(h[0], h[1], h[2], h[3]);
      *(short4*)(aLo + row * LSTR + ch * 4) = make_short4(l[0], l[1], l[2], l[3]);
    }
#pragma unroll
    for (int p = 0; p < 2; ++p) {
      int idx = tid + p * 256;
      int row = idx >> 2, ch = idx & 3;
      *(uint4*)(bHi + row * LSTR + ch * 8) = bRegH[p];
      *(uint4*)(bLo + row * LSTR + ch * 8) = bRegL[p];
    }
    __syncthreads();
    // prefetch next tile into regs (overlaps with MFMA below)
    if (kt + 1 < nk) {
      int kOff = (kt + 1) << 5;
#pragma unroll
      for (int p = 0; p < 4; ++p) {
        int idx = tid + p * 256;
        int row = idx >> 3, ch = idx & 7;
        aReg[p] = *(const float4*)(A + (long)(m0 + row) * K + kOff + ch * 4);
      }
#pragma unroll
      for (int p = 0; p < 2; ++p) {
        int idx = tid + p * 256;
        int row = idx >> 2, ch = idx & 3;
        long off = (long)(n0 + row) * K + kOff + ch * 8;
        bRegH[p] = *(const uint4*)(BtHi + off);
        bRegL[p] = *(const uint4*)(BtLo + off);
      }
    }
    // LDS -> fragments
    bf16x8_t ah[4], al[4], bh[4], bl[4];
#pragma unroll
    for (int f = 0; f < 4; ++f) {
      int arow = wr * 64 + f * 16 + lr;
      ah[f] = *(const bf16x8_t*)(aHi + arow * LSTR + lg * 8);
      al[f] = *(const bf16x8_t*)(aLo + arow * LSTR + lg * 8);
      int bcol = wc * 64 + f * 16 + lr;
      bh[f] = *(const bf16x8_t*)(bHi + bcol * LSTR + lg * 8);
      bl[f] = *(const bf16x8_t*)(bLo + bcol * LSTR + lg * 8);
    }
#pragma unroll
    for (int i = 0; i < 4; ++i)
#pragma unroll
      for (int j = 0; j < 4; ++j) {
        acc[i][j] = __builtin_amdgcn_mfma_f32_16x16x32_bf16(ah[i], bh[j], acc[i][j], 0, 0, 0);
        acc[i][j] = __builtin_amdgcn_mfma_f32_16x16x32_bf16(ah[i], bl[j], acc[i][j], 0, 0, 0);
        acc[i][j] = __builtin_amdgcn_mfma_f32_16x16x32_bf16(al[i], bh[j], acc[i][j], 0, 0, 0);
      }
  }

  // epilogue: C layout row=(lane>>4)*4+r, col=lane&15
#pragma unroll
  for (int i = 0; i < 4; ++i) {
    int mB = m0 + wr * 64 + i * 16 + lg * 4;
#pragma unroll
    for (int j = 0; j < 4; ++j) {
      int n = n0 + wc * 64 + j * 16 + lr;
      float bs = bias[n];
#pragma unroll
      for (int r = 0; r < 4; ++r) {
        int m = mB + r;
        float v = acc[i][j][r] + bs;
        if constexpr (EPI == EPI_RES) {
          ((float*)outp)[(long)m * N + n] = v + res[(long)m * N + n];
        } else if constexpr (EPI == EPI_RELU) {
          ((float*)outp)[(long)m * N + n] = fmaxf(v, 0.f);
        } else if constexpr (EPI == EPI_QK) {
          // qb/kb: [H][S][64]
          ((short*)outp)[(long)(n >> 6) * (long)M * 64 + (long)m * 64 + (n & 63)] = bf16_rne(v);
        } else { // EPI_VT: vT [H][64][S]
          ((short*)outp)[((long)(n >> 6) * 64 + (n & 63)) * (long)M + m] = bf16_rne(v);
        }
      }
    }
  }
}

// ---- flash attention: grid (S/128, H), 4 waves, each wave 32 q-rows, KV tiles of 64
__global__ __launch_bounds__(256)
void attn_kernel(const short* __restrict__ qb, const short* __restrict__ kb,
                 const short* __restrict__ vT, float* __restrict__ aout) {
  __shared__ float plds[4][32][68]; // per-wave P tile fp32, stride 272B (2-way = free)
  const int qt = blockIdx.x, h = blockIdx.y;
  const int tid = threadIdx.x;
  const int wave = tid >> 6, lane = tid & 63;
  const int lg = lane >> 4, lr = lane & 15;

  const short* qh = qb + (long)h * S_ * DK_;
  const short* kh = kb + (long)h * S_ * DK_;
  const short* vh = vT + (long)h * DK_ * S_;

  const int qrow0 = qt * 128 + wave * 32;

  bf16x8_t qf[2][2];
#pragma unroll
  for (int pf = 0; pf < 2; ++pf)
#pragma unroll
    for (int d = 0; d < 2; ++d)
      qf[pf][d] = *(const bf16x8_t*)(qh + (long)(qrow0 + pf * 16 + lr) * DK_ + d * 32 + lg * 8);

  float mrun[2][4], lrun[2][4];
  f32x4_t o[2][4];
#pragma unroll
  for (int pf = 0; pf < 2; ++pf) {
#pragma unroll
    for (int r = 0; r < 4; ++r) { mrun[pf][r] = -1e30f; lrun[pf][r] = 0.f; }
#pragma unroll
    for (int df = 0; df < 4; ++df) o[pf][df] = (f32x4_t){0.f, 0.f, 0.f, 0.f};
  }

  for (int kt = 0; kt < S_ / 64; ++kt) {
    f32x4_t sacc[2][4];
#pragma unroll
    for (int pf = 0; pf < 2; ++pf)
#pragma unroll
      for (int kc = 0; kc < 4; ++kc) sacc[pf][kc] = (f32x4_t){0.f, 0.f, 0.f, 0.f};

    // S = Q K^T (both operands row-major-contiguous loads)
#pragma unroll
    for (int kc = 0; kc < 4; ++kc) {
      const long krow = (long)(kt * 64 + kc * 16 + lr) * DK_;
      bf16x8_t k0 = *(const bf16x8_t*)(kh + krow + lg * 8);
      bf16x8_t k1 = *(const bf16x8_t*)(kh + krow + 32 + lg * 8);
#pragma unroll
      for (int pf = 0; pf < 2; ++pf) {
        sacc[pf][kc] = __builtin_amdgcn_mfma_f32_16x16x32_bf16(qf[pf][0], k0, sacc[pf][kc], 0, 0, 0);
        sacc[pf][kc] = __builtin_amdgcn_mfma_f32_16x16x32_bf16(qf[pf][1], k1, sacc[pf][kc], 0, 0, 0);
      }
    }
#pragma unroll
    for (int pf = 0; pf < 2; ++pf)
#pragma unroll
      for (int kc = 0; kc < 4; ++kc) sacc[pf][kc] *= 0.125f;

    // online softmax: row max via 16-lane shfl_xor reduce
    float ef[2][4];
#pragma unroll
    for (int pf = 0; pf < 2; ++pf) {
#pragma unroll
      for (int r = 0; r < 4; ++r) {
        float v = fmaxf(fmaxf(sacc[pf][0][r], sacc[pf][1][r]),
                        fmaxf(sacc[pf][2][r], sacc[pf][3][r]));
        v = fmaxf(v, __shfl_xor(v, 1));
        v = fmaxf(v, __shfl_xor(v, 2));
        v = fmaxf(v, __shfl_xor(v, 4));
        v = fmaxf(v, __shfl_xor(v, 8));
        float nm = fmaxf(mrun[pf][r], v);
        ef[pf][r] = __expf(mrun[pf][r] - nm);
        mrun[pf][r] = nm;
      }
    }
    // P = exp(S-m), row sums, stash P (fp32) in per-wave LDS
#pragma unroll
    for (int pf = 0; pf < 2; ++pf) {
#pragma unroll
      for (int r = 0; r < 4; ++r) {
        float ps = 0.f;
#pragma unroll
        for (int kc = 0; kc < 4; ++kc) {
          float p = __expf(sacc[pf][kc][r] - mrun[pf][r]);
          plds[wave][pf * 16 + lg * 4 + r][kc * 16 + lr] = p;
          ps += p;
        }
        ps += __shfl_xor(ps, 1);
        ps += __shfl_xor(ps, 2);
        ps += __shfl_xor(ps, 4);
        ps += __shfl_xor(ps, 8);
        lrun[pf][r] = lrun[pf][r] * ef[pf][r] + ps;
      }
    }
    // rescale O
#pragma unroll
    for (int pf = 0; pf < 2; ++pf)
#pragma unroll
      for (int df = 0; df < 4; ++df)
#pragma unroll
        for (int r = 0; r < 4; ++r) o[pf][df][r] *= ef[pf][r];

    // P back as A-fragments (bf16)
    bf16x8_t pA[2][2];
#pragma unroll
    for (int pf = 0; pf < 2; ++pf)
#pragma unroll
      for (int ks = 0; ks < 2; ++ks) {
        const float* pr = &plds[wave][pf * 16 + lr][ks * 32 + lg * 8];
        bf16x8_t t;
#pragma unroll
        for (int j = 0; j < 8; ++j) t[j] = bf16_rne(pr[j]);
        pA[pf][ks] = t;
      }
    // O += P V   (V pre-transposed: contiguous B-fragments)
#pragma unroll
    for (int df = 0; df < 4; ++df) {
      const long vrow = (long)(df * 16 + lr) * S_ + kt * 64;
      bf16x8_t v0 = *(const bf16x8_t*)(vh + vrow + lg * 8);
      bf16x8_t v1 = *(const bf16x8_t*)(vh + vrow + 32 + lg * 8);
#pragma unroll
      for (int pf = 0; pf < 2; ++pf) {
        o[pf][df] = __builtin_amdgcn_mfma_f32_16x16x32_bf16(pA[pf][0], v0, o[pf][df], 0, 0, 0);
        o[pf][df] = __builtin_amdgcn_mfma_f32_16x16x32_bf16(pA[pf][1], v1, o[pf][df], 0, 0, 0);
      }
    }
  }

  // normalize + store into concat layout [S][H*64]
#pragma unroll
  for (int pf = 0; pf < 2; ++pf)
#pragma unroll
    for (int df = 0; df < 4; ++df)
#pragma unroll
      for (int r = 0; r < 4; ++r) {
        int m = qrow0 + pf * 16 + lg * 4 + r;
        aout[(long)m * D_ + h * 64 + df * 16 + lr] = o[pf][df][r] / lrun[pf][r];
      }
}

// ---- rowwise LayerNorm over D=1024: one block per row
__global__ __launch_bounds__(256)
void ln_kernel(const float* __restrict__ x, const float* __restrict__ g,
               const float* __restrict__ b, float* __restrict__ out) {
  __shared__ float red[8];
  const int row = blockIdx.x;
  const int tid = threadIdx.x;
  float4 xv = *(const float4*)(x + (long)row * D_ + tid * 4);
  float s = xv.x + xv.y + xv.z + xv.w;
  float s2 = xv.x * xv.x + xv.y * xv.y + xv.z * xv.z + xv.w * xv.w;
#pragma unroll
  for (int m = 1; m < 64; m <<= 1) {
    s += __shfl_xor(s, m);
    s2 += __shfl_xor(s2, m);
  }
  int wave = tid >> 6, lane = tid & 63;
  if (lane == 0) { red[wave * 2] = s; red[wave * 2 + 1] = s2; }
  __syncthreads();
  s = red[0] + red[2] + red[4] + red[6];
  s2 = red[1] + red[3] + red[5] + red[7];
  float mu = s * (1.f / D_);
  float var = s2 * (1.f / D_) - mu * mu;
  float rs = rsqrtf(var + 1e-5f);
  float4 gv = *(const float4*)(g + tid * 4);
  float4 bv = *(const float4*)(b + tid * 4);
  float4 ov;
  ov.x = (xv.x - mu) * rs * gv.x + bv.x;
  ov.y = (xv.y - mu) * rs * gv.y + bv.y;
  ov.z = (xv.z - mu) * rs * gv.z + bv.z;
  ov.w = (xv.w - mu) * rs * gv.w + bv.w;
  *(float4*)(out + (long)row * D_ + tid * 4) = ov;
}

extern "C" void kernel_launch(void* const* d_in, const int* in_sizes, int n_in,
                              void* d_out, int out_size, void* d_ws, size_t ws_size,
                              hipStream_t stream) {
  const float* src  = (const float*)d_in[0];
  const float* Wq   = (const float*)d_in[1];
  const float* bq   = (const float*)d_in[2];
  const float* Wk   = (const float*)d_in[3];
  const float* bk   = (const float*)d_in[4];
  const float* Wv   = (const float*)d_in[5];
  const float* bv   = (const float*)d_in[6];
  const float* Wo   = (const float*)d_in[7];
  const float* bo   = (const float*)d_in[8];
  const float* ln1g = (const float*)d_in[9];
  const float* ln1b = (const float*)d_in[10];
  const float* W1   = (const float*)d_in[11];
  const float* b1   = (const float*)d_in[12];
  const float* W2   = (const float*)d_in[13];
  const float* b2   = (const float*)d_in[14];
  const float* ln2g = (const float*)d_in[15];
  const float* ln2b = (const float*)d_in[16];
  float* out = (float*)d_out;

  char* w = (char*)d_ws;
  auto take = [&](size_t bytes) {
    char* p = w;
    w += (bytes + 255) & ~(size_t)255;
    return p;
  };
  short* wqtH = (short*)take((size_t)D_ * D_ * 2);
  short* wqtL = (short*)take((size_t)D_ * D_ * 2);
  short* wktH = (short*)take((size_t)D_ * D_ * 2);
  short* wktL = (short*)take((size_t)D_ * D_ * 2);
  short* wvtH = (short*)take((size_t)D_ * D_ * 2);
  short* wvtL = (short*)take((size_t)D_ * D_ * 2);
  short* wotH = (short*)take((size_t)D_ * D_ * 2);
  short* wotL = (short*)take((size_t)D_ * D_ * 2);
  short* w1tH = (short*)take((size_t)D_ * F_ * 2);
  short* w1tL = (short*)take((size_t)D_ * F_ * 2);
  short* w2tH = (short*)take((size_t)F_ * D_ * 2);
  short* w2tL = (short*)take((size_t)F_ * D_ * 2);
  short* qb   = (short*)take((size_t)H_ * S_ * DK_ * 2);
  short* kbuf = (short*)take((size_t)H_ * S_ * DK_ * 2);
  short* vTb  = (short*)take((size_t)H_ * DK_ * S_ * 2);
  float* attnB = (float*)take((size_t)S_ * D_ * 4);   // reused as pre2 later
  float* pre1 = (float*)take((size_t)S_ * D_ * 4);
  float* x1   = (float*)take((size_t)S_ * D_ * 4);
  float* h1   = (float*)take((size_t)S_ * F_ * 4);
  float* pre2 = attnB;

  dim3 blk(256);

  // weight prep (transpose + hi/lo split)
  prep_w<1><<<dim3(D_ / 32, D_ / 32), blk, 0, stream>>>(Wq, wqtH, wqtL, D_, D_);
  prep_w<1><<<dim3(D_ / 32, D_ / 32), blk, 0, stream>>>(Wk, wktH, wktL, D_, D_);
  prep_w<1><<<dim3(D_ / 32, D_ / 32), blk, 0, stream>>>(Wv, wvtH, wvtL, D_, D_);
  prep_w<0><<<dim3(D_ / 32, D_ / 32), blk, 0, stream>>>(Wo, wotH, wotL, D_, D_);
  prep_w<0><<<dim3(F_ / 32, D_ / 32), blk, 0, stream>>>(W1, w1tH, w1tL, D_, F_);
  prep_w<0><<<dim3(D_ / 32, F_ / 32), blk, 0, stream>>>(W2, w2tH, w2tL, F_, D_);

  // QKV projections -> bf16 (v transposed per head)
  gemm128<EPI_QK><<<dim3(S_ / 128, D_ / 128), blk, 0, stream>>>(
      src, D_, wqtH, wqtL, bq, nullptr, qb, S_, D_);
  gemm128<EPI_QK><<<dim3(S_ / 128, D_ / 128), blk, 0, stream>>>(
      src, D_, wktH, wktL, bk, nullptr, kbuf, S_, D_);
  gemm128<EPI_VT><<<dim3(S_ / 128, D_ / 128), blk, 0, stream>>>(
      src, D_, wvtH, wvtL, bv, nullptr, vTb, S_, D_);

  // flash attention -> concat [S][H*64]
  attn_kernel<<<dim3(S_ / 128, H_), blk, 0, stream>>>(qb, kbuf, vTb, attnB);

  // Wo projection + residual, then LN1
  gemm128<EPI_RES><<<dim3(S_ / 128, D_ / 128), blk, 0, stream>>>(
      attnB, D_, wotH, wotL, bo, src, pre1, S_, D_);
  ln_kernel<<<dim3(S_), blk, 0, stream>>>(pre1, ln1g, ln1b, x1);

  // FFN
  gemm128<EPI_RELU><<<dim3(S_ / 128, F_ / 128), blk, 0, stream>>>(
      x1, D_, w1tH, w1tL, b1, nullptr, h1, S_, F_);
  gemm128<EPI_RES><<<dim3(S_ / 128, D_ / 128), blk, 0, stream>>>(
      h1, F_, w2tH, w2tL, b2, x1, pre2, S_, D_);
  ln_kernel<<<dim3(S_), blk, 0, stream>>>(pre2, ln2g, ln2b, out);

  (void)in_sizes; (void)n_in; (void)out_size; (void)ws_size;
}

// Round 2
// 952.777 us; speedup vs baseline: 1.1479x; 1.1479x over previous
//
#include <hip/hip_runtime.h>
#include <hip/hip_bf16.h>

#define S_ 4096
#define D_ 1024
#define H_ 16
#define DK_ 64
#define F_ 4096

typedef short bf16x8_t __attribute__((ext_vector_type(8)));
typedef float f32x4_t __attribute__((ext_vector_type(4)));

#define MFMA16(a, b, c) __builtin_amdgcn_mfma_f32_16x16x32_bf16(a, b, c, 0, 0, 0)

__device__ __forceinline__ short f2bf(float f) {
  union { float f; unsigned u; } a; a.f = f;
  unsigned r = a.u + 0x7fffu + ((a.u >> 16) & 1u);
  return (short)(r >> 16);
}
__device__ __forceinline__ float bf2f(short s) {
  union { unsigned u; float f; } a; a.u = ((unsigned)(unsigned short)s) << 16;
  return a.f;
}

__device__ __forceinline__ void async_copy16(short* ldsDst, const short* gSrc) {
  __builtin_amdgcn_global_load_lds(
      (const __attribute__((address_space(1))) unsigned int*)gSrc,
      (__attribute__((address_space(3))) unsigned int*)ldsDst, 16, 0, 0);
}

// ---- weight prep: fp32 [K][N] (flat) or [H][K][64] (head) -> bf16 hi/lo in [N][K]
template<int HEADMODE>
__global__ __launch_bounds__(256)
void prep_w(const float* __restrict__ W, short* __restrict__ outHi,
            short* __restrict__ outLo, int K, int N) {
  __shared__ float t[32][33];
  int n0 = blockIdx.x * 32, k0 = blockIdx.y * 32;
  int tid = threadIdx.x;
  int cin = tid & 31, kin = tid >> 5;
#pragma unroll
  for (int i = 0; i < 4; ++i) {
    int k = kin + i * 8;
    int n = n0 + cin;
    long srcIdx;
    if (HEADMODE) srcIdx = ((long)(n >> 6) * K + (k0 + k)) * 64 + (n & 63);
    else          srcIdx = (long)(k0 + k) * N + n;
    t[k][cin] = W[srcIdx];
  }
  __syncthreads();
  int kout = tid & 31, cb = tid >> 5;
#pragma unroll
  for (int i = 0; i < 4; ++i) {
    int c = cb + i * 8;
    float v = t[kout][c];
    short hi = f2bf(v);
    short lo = f2bf(v - bf2f(hi));
    long dst = (long)(n0 + c) * K + (k0 + kout);
    outHi[dst] = hi;
    outLo[dst] = lo;
  }
}

// ---- fp32 -> bf16 hi/lo elementwise
__global__ __launch_bounds__(256)
void cvt_hl(const float* __restrict__ x, short* __restrict__ h, short* __restrict__ l) {
  long i = ((long)blockIdx.x * 256 + threadIdx.x) * 4;
  float4 v = *(const float4*)(x + i);
  short4 hh, ll;
  hh.x = f2bf(v.x); ll.x = f2bf(v.x - bf2f(hh.x));
  hh.y = f2bf(v.y); ll.y = f2bf(v.y - bf2f(hh.y));
  hh.z = f2bf(v.z); ll.z = f2bf(v.z - bf2f(hh.z));
  hh.w = f2bf(v.w); ll.w = f2bf(v.w - bf2f(hh.w));
  *(short4*)(h + i) = hh;
  *(short4*)(l + i) = ll;
}

// ---- bf16x3 GEMM, 128x128 tile, BK=32, global_load_lds staging, swizzled LDS
#define EPI_QKV 0
#define EPI_PART 1
#define EPI_RELUHL 2

template<int EPI, int SPLITK>
__global__ __launch_bounds__(256)
void gemm_bf3(const short* __restrict__ AH, const short* __restrict__ AL,
              const short* __restrict__ BH, const short* __restrict__ BL,
              int K, int M, int N,
              const float* __restrict__ bq_, const float* __restrict__ bk_,
              const float* __restrict__ bv_,
              void* __restrict__ out0, void* __restrict__ out1) {
  __shared__ short lds[16384];  // 32 KB: AH|AL|BH|BL panels, each [128][32]
  const int m0 = blockIdx.x * 128, n0 = blockIdx.y * 128;
  const int tid = threadIdx.x;
  const int wave = tid >> 6, lane = tid & 63;
  const int wr = wave >> 1, wc = wave & 1;
  const int lg = lane >> 4, lr = lane & 15;
  const int kLen = (SPLITK > 1) ? (K / SPLITK) : K;
  const long kBase = (SPLITK > 1) ? (long)blockIdx.z * kLen : 0;
  const int nk = kLen >> 5;

  const short* gAH = AH + (long)m0 * K + kBase;
  const short* gAL = AL + (long)m0 * K + kBase;
  const short* gBH = BH + (long)n0 * K + kBase;
  const short* gBL = BL + (long)n0 * K + kBase;

  f32x4_t acc[4][4];
#pragma unroll
  for (int i = 0; i < 4; ++i)
#pragma unroll
    for (int j = 0; j < 4; ++j)
      acc[i][j] = (f32x4_t){0.f, 0.f, 0.f, 0.f};

  for (int kt = 0; kt < nk; ++kt) {
    // stage 4 panels via global_load_lds (linear LDS, pre-swizzled global source)
#pragma unroll
    for (int p = 0; p < 8; ++p) {
      const short* gb = (p < 2) ? gAH : (p < 4) ? gAL : (p < 6) ? gBH : gBL;
      int w = ((p & 1) << 8) | tid;
      int row = w >> 2;
      int gsw = ((w & 3) ^ (row & 3)) << 3;  // XOR granule swizzle
      async_copy16(lds + (((p << 8) | tid) << 3),
                   gb + (long)row * K + (kt << 5) + gsw);
    }
    __syncthreads();
    bf16x8_t ah[4], al[4], bh[4], bl[4];
#pragma unroll
    for (int f = 0; f < 4; ++f) {
      int ar = wr * 64 + f * 16 + lr;
      int ag = (lg ^ (ar & 3)) << 3;
      ah[f] = *(const bf16x8_t*)(lds + ar * 32 + ag);
      al[f] = *(const bf16x8_t*)(lds + 4096 + ar * 32 + ag);
      int br = wc * 64 + f * 16 + lr;
      int bg = (lg ^ (br & 3)) << 3;
      bh[f] = *(const bf16x8_t*)(lds + 8192 + br * 32 + bg);
      bl[f] = *(const bf16x8_t*)(lds + 12288 + br * 32 + bg);
    }
#pragma unroll
    for (int i = 0; i < 4; ++i)
#pragma unroll
      for (int j = 0; j < 4; ++j) {
        acc[i][j] = MFMA16(ah[i], bh[j], acc[i][j]);
        acc[i][j] = MFMA16(ah[i], bl[j], acc[i][j]);
        acc[i][j] = MFMA16(al[i], bh[j], acc[i][j]);
      }
    __syncthreads();
  }

  // epilogue: C row = mB + r, col = n
#pragma unroll
  for (int i = 0; i < 4; ++i) {
    int mB = m0 + wr * 64 + i * 16 + lg * 4;
#pragma unroll
    for (int j = 0; j < 4; ++j) {
      int n = n0 + wc * 64 + j * 16 + lr;
      if constexpr (EPI == EPI_PART) {
        float* outp = (float*)out0 + (long)blockIdx.z * M * N;
#pragma unroll
        for (int r = 0; r < 4; ++r)
          outp[(long)(mB + r) * N + n] = acc[i][j][r];
      } else if constexpr (EPI == EPI_RELUHL) {
        float bs = bq_[n];
        short* oH = (short*)out0;
        short* oL = (short*)out1;
#pragma unroll
        for (int r = 0; r < 4; ++r) {
          float v = fmaxf(acc[i][j][r] + bs, 0.f);
          short hi = f2bf(v);
          long idx = (long)(mB + r) * N + n;
          oH[idx] = hi;
          oL[idx] = f2bf(v - bf2f(hi));
        }
      } else {  // EPI_QKV: q|k -> qk[S][2048] (q scaled 0.125), v -> vT[1024][S]
        short* qko = (short*)out0;
        short* vto = (short*)out1;
        if (n < 1024) {
          float bs = bq_[n];
#pragma unroll
          for (int r = 0; r < 4; ++r)
            qko[(long)(mB + r) * 2048 + n] = f2bf((acc[i][j][r] + bs) * 0.125f);
        } else if (n < 2048) {
          float bs = bk_[n - 1024];
#pragma unroll
          for (int r = 0; r < 4; ++r)
            qko[(long)(mB + r) * 2048 + n] = f2bf(acc[i][j][r] + bs);
        } else {
          float bs = bv_[n - 2048];
          short4 pk;
          pk.x = f2bf(acc[i][j][0] + bs);
          pk.y = f2bf(acc[i][j][1] + bs);
          pk.z = f2bf(acc[i][j][2] + bs);
          pk.w = f2bf(acc[i][j][3] + bs);
          *(short4*)(vto + (long)(n - 2048) * S_ + mB) = pk;
        }
      }
    }
  }
}

// ---- flash attention: grid (S/64, H), 4 waves, each wave 16 q-rows, KV tiles of 64
__global__ __launch_bounds__(256)
void attn_kernel(const short* __restrict__ qk, const short* __restrict__ vT,
                 short* __restrict__ attnH, short* __restrict__ attnL) {
  __shared__ short plds[4][16][72];  // per-wave P tile bf16
  const int qt = blockIdx.x, h = blockIdx.y;
  const int tid = threadIdx.x;
  const int wave = tid >> 6, lane = tid & 63;
  const int lg = lane >> 4, lr = lane & 15;
  const int qrow0 = qt * 64 + wave * 16;

  const short* qbase = qk + (long)qrow0 * 2048 + h * 64;
  const short* kbase = qk + 1024 + h * 64;
  const short* vh = vT + (long)h * 64 * S_;

  bf16x8_t qf0 = *(const bf16x8_t*)(qbase + (long)lr * 2048 + lg * 8);
  bf16x8_t qf1 = *(const bf16x8_t*)(qbase + (long)lr * 2048 + 32 + lg * 8);

  float mrun[4], lrun[4];
  f32x4_t o[4];
#pragma unroll
  for (int r = 0; r < 4; ++r) { mrun[r] = -1e30f; lrun[r] = 0.f; }
#pragma unroll
  for (int df = 0; df < 4; ++df) o[df] = (f32x4_t){0.f, 0.f, 0.f, 0.f};

  for (int kt = 0; kt < S_ / 64; ++kt) {
    f32x4_t sacc[4];
#pragma unroll
    for (int kc = 0; kc < 4; ++kc) sacc[kc] = (f32x4_t){0.f, 0.f, 0.f, 0.f};

    __builtin_amdgcn_s_setprio(1);
#pragma unroll
    for (int kc = 0; kc < 4; ++kc) {
      const short* kr = kbase + (long)(kt * 64 + kc * 16 + lr) * 2048;
      bf16x8_t k0 = *(const bf16x8_t*)(kr + lg * 8);
      bf16x8_t k1 = *(const bf16x8_t*)(kr + 32 + lg * 8);
      sacc[kc] = MFMA16(qf0, k0, sacc[kc]);
      sacc[kc] = MFMA16(qf1, k1, sacc[kc]);
    }
    __builtin_amdgcn_s_setprio(0);

    float ef[4];
#pragma unroll
    for (int r = 0; r < 4; ++r) {
      float v = fmaxf(fmaxf(sacc[0][r], sacc[1][r]), fmaxf(sacc[2][r], sacc[3][r]));
      v = fmaxf(v, __shfl_xor(v, 1));
      v = fmaxf(v, __shfl_xor(v, 2));
      v = fmaxf(v, __shfl_xor(v, 4));
      v = fmaxf(v, __shfl_xor(v, 8));
      float nm = fmaxf(mrun[r], v);
      ef[r] = __expf(mrun[r] - nm);
      mrun[r] = nm;
      float ps = 0.f;
#pragma unroll
      for (int kc = 0; kc < 4; ++kc) {
        float p = __expf(sacc[kc][r] - nm);
        plds[wave][lg * 4 + r][kc * 16 + lr] = f2bf(p);
        ps += p;
      }
      ps += __shfl_xor(ps, 1);
      ps += __shfl_xor(ps, 2);
      ps += __shfl_xor(ps, 4);
      ps += __shfl_xor(ps, 8);
      lrun[r] = lrun[r] * ef[r] + ps;
    }
#pragma unroll
    for (int df = 0; df < 4; ++df)
#pragma unroll
      for (int r = 0; r < 4; ++r) o[df][r] *= ef[r];

    bf16x8_t pA0 = *(const bf16x8_t*)&plds[wave][lr][lg * 8];
    bf16x8_t pA1 = *(const bf16x8_t*)&plds[wave][lr][32 + lg * 8];

    __builtin_amdgcn_s_setprio(1);
#pragma unroll
    for (int df = 0; df < 4; ++df) {
      const short* vr = vh + (long)(df * 16 + lr) * S_ + kt * 64;
      bf16x8_t v0 = *(const bf16x8_t*)(vr + lg * 8);
      bf16x8_t v1 = *(const bf16x8_t*)(vr + 32 + lg * 8);
      o[df] = MFMA16(pA0, v0, o[df]);
      o[df] = MFMA16(pA1, v1, o[df]);
    }
    __builtin_amdgcn_s_setprio(0);
  }

#pragma unroll
  for (int r = 0; r < 4; ++r) {
    float inv = 1.0f / lrun[r];
    int m = qrow0 + lg * 4 + r;
#pragma unroll
    for (int df = 0; df < 4; ++df) {
      float v = o[df][r] * inv;
      short hi = f2bf(v);
      long idx = (long)m * D_ + h * 64 + df * 16 + lr;
      attnH[idx] = hi;
      attnL[idx] = f2bf(v - bf2f(hi));
    }
  }
}

// ---- fused: x = pA + pB + res + bias; LayerNorm; optional hi/lo bf16 outputs
template<int WHL>
__global__ __launch_bounds__(256)
void ln_fused(const float* __restrict__ pA, const float* __restrict__ pB,
              const float* __restrict__ res, const float* __restrict__ bias,
              const float* __restrict__ g, const float* __restrict__ b,
              float* __restrict__ outF, short* __restrict__ outH,
              short* __restrict__ outL) {
  __shared__ float red[8];
  const int row = blockIdx.x, tid = threadIdx.x;
  const long base = (long)row * D_ + tid * 4;
  float4 a = *(const float4*)(pA + base);
  float4 c = *(const float4*)(pB + base);
  float4 rr = *(const float4*)(res + base);
  float4 bb = *(const float4*)(bias + tid * 4);
  float x0 = a.x + c.x + rr.x + bb.x;
  float x1v = a.y + c.y + rr.y + bb.y;
  float x2v = a.z + c.z + rr.z + bb.z;
  float x3v = a.w + c.w + rr.w + bb.w;
  float s = x0 + x1v + x2v + x3v;
  float s2 = x0 * x0 + x1v * x1v + x2v * x2v + x3v * x3v;
#pragma unroll
  for (int m = 1; m < 64; m <<= 1) {
    s += __shfl_xor(s, m);
    s2 += __shfl_xor(s2, m);
  }
  int wave = tid >> 6, lane = tid & 63;
  if (lane == 0) { red[wave * 2] = s; red[wave * 2 + 1] = s2; }
  __syncthreads();
  s = red[0] + red[2] + red[4] + red[6];
  s2 = red[1] + red[3] + red[5] + red[7];
  float mu = s * (1.f / D_);
  float var = s2 * (1.f / D_) - mu * mu;
  float rs = rsqrtf(var + 1e-5f);
  float4 gv = *(const float4*)(g + tid * 4);
  float4 bv = *(const float4*)(b + tid * 4);
  float y0 = (x0 - mu) * rs * gv.x + bv.x;
  float y1 = (x1v - mu) * rs * gv.y + bv.y;
  float y2 = (x2v - mu) * rs * gv.z + bv.z;
  float y3 = (x3v - mu) * rs * gv.w + bv.w;
  float4 ov = {y0, y1, y2, y3};
  *(float4*)(outF + base) = ov;
  if constexpr (WHL) {
    short4 hh, ll;
    hh.x = f2bf(y0); ll.x = f2bf(y0 - bf2f(hh.x));
    hh.y = f2bf(y1); ll.y = f2bf(y1 - bf2f(hh.y));
    hh.z = f2bf(y2); ll.z = f2bf(y2 - bf2f(hh.z));
    hh.w = f2bf(y3); ll.w = f2bf(y3 - bf2f(hh.w));
    *(short4*)(outH + base) = hh;
    *(short4*)(outL + base) = ll;
  }
}

extern "C" void kernel_launch(void* const* d_in, const int* in_sizes, int n_in,
                              void* d_out, int out_size, void* d_ws, size_t ws_size,
                              hipStream_t stream) {
  const float* src  = (const float*)d_in[0];
  const float* Wq   = (const float*)d_in[1];
  const float* bq   = (const float*)d_in[2];
  const float* Wk   = (const float*)d_in[3];
  const float* bk   = (const float*)d_in[4];
  const float* Wv   = (const float*)d_in[5];
  const float* bv   = (const float*)d_in[6];
  const float* Wo   = (const float*)d_in[7];
  const float* bo   = (const float*)d_in[8];
  const float* ln1g = (const float*)d_in[9];
  const float* ln1b = (const float*)d_in[10];
  const float* W1   = (const float*)d_in[11];
  const float* b1   = (const float*)d_in[12];
  const float* W2   = (const float*)d_in[13];
  const float* b2   = (const float*)d_in[14];
  const float* ln2g = (const float*)d_in[15];
  const float* ln2b = (const float*)d_in[16];
  float* out = (float*)d_out;

  const size_t SD = (size_t)S_ * D_;
  const size_t SF = (size_t)S_ * F_;

  char* w = (char*)d_ws;
  auto take = [&](size_t bytes) {
    char* p = w;
    w += (bytes + 255) & ~(size_t)255;
    return p;
  };
  // region A (aliased by W2 partials after attention is done):
  short* srcH  = (short*)take(SD * 2);
  short* srcL  = (short*)take(SD * 2);
  short* qkb   = (short*)take((size_t)S_ * 2048 * 2);
  short* vTb   = (short*)take((size_t)D_ * S_ * 2);
  // region B (aliased by Wo partials before W1 writes h1):
  short* h1H   = (short*)take(SF * 2);
  short* h1L   = (short*)take(SF * 2);
  // weights
  short* wqkvH = (short*)take((size_t)3072 * D_ * 2);
  short* wqkvL = (short*)take((size_t)3072 * D_ * 2);
  short* woH   = (short*)take((size_t)D_ * D_ * 2);
  short* woL   = (short*)take((size_t)D_ * D_ * 2);
  short* w1H   = (short*)take((size_t)F_ * D_ * 2);
  short* w1L   = (short*)take((size_t)F_ * D_ * 2);
  short* w2H   = (short*)take((size_t)D_ * F_ * 2);
  short* w2L   = (short*)take((size_t)D_ * F_ * 2);
  // activations
  short* attnH = (short*)take(SD * 2);
  short* attnL = (short*)take(SD * 2);
  float* x1    = (float*)take(SD * 4);
  short* x1H   = (short*)take(SD * 2);
  short* x1L   = (short*)take(SD * 2);

  float* partWo = (float*)h1H;   // 2*SD fp32 = 33.5 MB, fits in h1H (SF*2)
  float* partW2 = (float*)srcH;  // 2*SD fp32 spans srcH+srcL+qkb, all dead by then

  dim3 blk(256);

  // weight prep (transpose + hi/lo split); QKV into one [3072][1024] buffer
  prep_w<1><<<dim3(32, 32), blk, 0, stream>>>(Wq, wqkvH, wqkvL, D_, D_);
  prep_w<1><<<dim3(32, 32), blk, 0, stream>>>(Wk, wqkvH + (size_t)1024 * D_,
                                              wqkvL + (size_t)1024 * D_, D_, D_);
  prep_w<1><<<dim3(32, 32), blk, 0, stream>>>(Wv, wqkvH + (size_t)2048 * D_,
                                              wqkvL + (size_t)2048 * D_, D_, D_);
  prep_w<0><<<dim3(32, 32), blk, 0, stream>>>(Wo, woH, woL, D_, D_);
  prep_w<0><<<dim3(128, 32), blk, 0, stream>>>(W1, w1H, w1L, D_, F_);
  prep_w<0><<<dim3(32, 128), blk, 0, stream>>>(W2, w2H, w2L, F_, D_);

  // src -> hi/lo
  cvt_hl<<<dim3(4096), blk, 0, stream>>>(src, srcH, srcL);

  // fused QKV projection (q pre-scaled by 1/8, v transposed per head)
  gemm_bf3<EPI_QKV, 1><<<dim3(32, 24), blk, 0, stream>>>(
      srcH, srcL, wqkvH, wqkvL, D_, S_, 3072, bq, bk, bv, qkb, vTb);

  // flash attention -> attn hi/lo [S][1024]
  attn_kernel<<<dim3(64, 16), blk, 0, stream>>>(qkb, vTb, attnH, attnL);

  // Wo projection, split-K=2 partials; LN1 fuses partials + src + bo
  gemm_bf3<EPI_PART, 2><<<dim3(32, 8, 2), blk, 0, stream>>>(
      attnH, attnL, woH, woL, D_, S_, D_, nullptr, nullptr, nullptr, partWo, nullptr);
  ln_fused<1><<<dim3(S_), blk, 0, stream>>>(partWo, partWo + SD, src, bo,
                                            ln1g, ln1b, x1, x1H, x1L);

  // FFN
  gemm_bf3<EPI_RELUHL, 1><<<dim3(32, 32), blk, 0, stream>>>(
      x1H, x1L, w1H, w1L, D_, S_, F_, b1, nullptr, nullptr, h1H, h1L);
  gemm_bf3<EPI_PART, 2><<<dim3(32, 8, 2), blk, 0, stream>>>(
      h1H, h1L, w2H, w2L, F_, S_, D_, nullptr, nullptr, nullptr, partW2, nullptr);
  ln_fused<0><<<dim3(S_), blk, 0, stream>>>(partW2, partW2 + SD, x1, b2,
                                            ln2g, ln2b, out, nullptr, nullptr);

  (void)in_sizes; (void)n_in; (void)out_size; (void)ws_size;
}

// Round 4
// 744.026 us; speedup vs baseline: 1.4700x; 1.2806x over previous
//
#include <hip/hip_runtime.h>
#include <hip/hip_bf16.h>

#define S_ 4096
#define D_ 1024
#define H_ 16
#define DK_ 64
#define F_ 4096

typedef short bf16x8_t __attribute__((ext_vector_type(8)));
typedef float f32x4_t __attribute__((ext_vector_type(4)));

#define MFMA16(a, b, c) __builtin_amdgcn_mfma_f32_16x16x32_bf16(a, b, c, 0, 0, 0)

// q-scale: 1/sqrt(64) * log2(e)  (softmax done in base-2)
#define QSCALE 0.1803368801111243f

__device__ __forceinline__ short f2bf(float f) {
  union { float f; unsigned u; } a; a.f = f;
  unsigned r = a.u + 0x7fffu + ((a.u >> 16) & 1u);
  return (short)(r >> 16);
}
__device__ __forceinline__ float bf2f(short s) {
  union { unsigned u; float f; } a; a.u = ((unsigned)(unsigned short)s) << 16;
  return a.f;
}
__device__ __forceinline__ unsigned cvtpk_bf16(float lo, float hi) {
  unsigned w;
  asm("v_cvt_pk_bf16_f32 %0, %1, %2" : "=v"(w) : "v"(lo), "v"(hi));
  return w;
}

__device__ __forceinline__ void async_copy16(short* ldsDst, const short* gSrc) {
  __builtin_amdgcn_global_load_lds(
      (const __attribute__((address_space(1))) unsigned int*)gSrc,
      (__attribute__((address_space(3))) unsigned int*)ldsDst, 16, 0, 0);
}

// ---- weight prep: fp32 [K][N] (flat) or [H][K][64] (head) -> bf16 hi/lo in [N][K]
template<int HEADMODE>
__global__ __launch_bounds__(256)
void prep_w(const float* __restrict__ W, short* __restrict__ outHi,
            short* __restrict__ outLo, int K, int N) {
  __shared__ float t[32][33];
  int n0 = blockIdx.x * 32, k0 = blockIdx.y * 32;
  int tid = threadIdx.x;
  int cin = tid & 31, kin = tid >> 5;
#pragma unroll
  for (int i = 0; i < 4; ++i) {
    int k = kin + i * 8;
    int n = n0 + cin;
    long srcIdx;
    if (HEADMODE) srcIdx = ((long)(n >> 6) * K + (k0 + k)) * 64 + (n & 63);
    else          srcIdx = (long)(k0 + k) * N + n;
    t[k][cin] = W[srcIdx];
  }
  __syncthreads();
  int kout = tid & 31, cb = tid >> 5;
#pragma unroll
  for (int i = 0; i < 4; ++i) {
    int c = cb + i * 8;
    float v = t[kout][c];
    short hi = f2bf(v);
    short lo = f2bf(v - bf2f(hi));
    long dst = (long)(n0 + c) * K + (k0 + kout);
    outHi[dst] = hi;
    outLo[dst] = lo;
  }
}

// ---- fp32 -> bf16 hi/lo elementwise
__global__ __launch_bounds__(256)
void cvt_hl(const float* __restrict__ x, short* __restrict__ h, short* __restrict__ l) {
  long i = ((long)blockIdx.x * 256 + threadIdx.x) * 4;
  float4 v = *(const float4*)(x + i);
  short4 hh, ll;
  hh.x = f2bf(v.x); ll.x = f2bf(v.x - bf2f(hh.x));
  hh.y = f2bf(v.y); ll.y = f2bf(v.y - bf2f(hh.y));
  hh.z = f2bf(v.z); ll.z = f2bf(v.z - bf2f(hh.z));
  hh.w = f2bf(v.w); ll.w = f2bf(v.w - bf2f(hh.w));
  *(short4*)(h + i) = hh;
  *(short4*)(l + i) = ll;
}

// ---- bf16x3 GEMM, 128x128 tile, BK=32, global_load_lds staging, swizzled LDS
#define EPI_QKV 0
#define EPI_PART 1
#define EPI_RELUHL 2

template<int EPI, int SPLITK>
__global__ __launch_bounds__(256)
void gemm_bf3(const short* __restrict__ AH, const short* __restrict__ AL,
              const short* __restrict__ BH, const short* __restrict__ BL,
              int K, int M, int N,
              const float* __restrict__ bq_, const float* __restrict__ bk_,
              const float* __restrict__ bv_,
              void* __restrict__ out0, void* __restrict__ out1) {
  __shared__ short lds[16384];  // 32 KB: AH|AL|BH|BL panels, each [128][32]
  const int m0 = blockIdx.x * 128, n0 = blockIdx.y * 128;
  const int tid = threadIdx.x;
  const int wave = tid >> 6, lane = tid & 63;
  const int wr = wave >> 1, wc = wave & 1;
  const int lg = lane >> 4, lr = lane & 15;
  const int kLen = (SPLITK > 1) ? (K / SPLITK) : K;
  const long kBase = (SPLITK > 1) ? (long)blockIdx.z * kLen : 0;
  const int nk = kLen >> 5;

  const short* gAH = AH + (long)m0 * K + kBase;
  const short* gAL = AL + (long)m0 * K + kBase;
  const short* gBH = BH + (long)n0 * K + kBase;
  const short* gBL = BL + (long)n0 * K + kBase;

  f32x4_t acc[4][4];
#pragma unroll
  for (int i = 0; i < 4; ++i)
#pragma unroll
    for (int j = 0; j < 4; ++j)
      acc[i][j] = (f32x4_t){0.f, 0.f, 0.f, 0.f};

  for (int kt = 0; kt < nk; ++kt) {
    // stage 4 panels via global_load_lds (linear LDS, pre-swizzled global source)
#pragma unroll
    for (int p = 0; p < 8; ++p) {
      const short* gb = (p < 2) ? gAH : (p < 4) ? gAL : (p < 6) ? gBH : gBL;
      int w = ((p & 1) << 8) | tid;
      int row = w >> 2;
      int gsw = ((w & 3) ^ (row & 3)) << 3;  // XOR granule swizzle
      async_copy16(lds + (((p << 8) | tid) << 3),
                   gb + (long)row * K + (kt << 5) + gsw);
    }
    __syncthreads();
    bf16x8_t ah[4], al[4], bh[4], bl[4];
#pragma unroll
    for (int f = 0; f < 4; ++f) {
      int ar = wr * 64 + f * 16 + lr;
      int ag = (lg ^ (ar & 3)) << 3;
      ah[f] = *(const bf16x8_t*)(lds + ar * 32 + ag);
      al[f] = *(const bf16x8_t*)(lds + 4096 + ar * 32 + ag);
      int br = wc * 64 + f * 16 + lr;
      int bg = (lg ^ (br & 3)) << 3;
      bh[f] = *(const bf16x8_t*)(lds + 8192 + br * 32 + bg);
      bl[f] = *(const bf16x8_t*)(lds + 12288 + br * 32 + bg);
    }
#pragma unroll
    for (int i = 0; i < 4; ++i)
#pragma unroll
      for (int j = 0; j < 4; ++j) {
        acc[i][j] = MFMA16(ah[i], bh[j], acc[i][j]);
        acc[i][j] = MFMA16(ah[i], bl[j], acc[i][j]);
        acc[i][j] = MFMA16(al[i], bh[j], acc[i][j]);
      }
    __syncthreads();
  }

  // epilogue: C row = mB + r, col = n
#pragma unroll
  for (int i = 0; i < 4; ++i) {
    int mB = m0 + wr * 64 + i * 16 + lg * 4;
#pragma unroll
    for (int j = 0; j < 4; ++j) {
      int n = n0 + wc * 64 + j * 16 + lr;
      if constexpr (EPI == EPI_PART) {
        float* outp = (float*)out0 + (long)blockIdx.z * M * N;
#pragma unroll
        for (int r = 0; r < 4; ++r)
          outp[(long)(mB + r) * N + n] = acc[i][j][r];
      } else if constexpr (EPI == EPI_RELUHL) {
        float bs = bq_[n];
        short* oH = (short*)out0;
        short* oL = (short*)out1;
#pragma unroll
        for (int r = 0; r < 4; ++r) {
          float v = fmaxf(acc[i][j][r] + bs, 0.f);
          short hi = f2bf(v);
          long idx = (long)(mB + r) * N + n;
          oH[idx] = hi;
          oL[idx] = f2bf(v - bf2f(hi));
        }
      } else {  // EPI_QKV: q|k -> qk[S][2048] (q scaled QSCALE), v -> vT[1024][S]
        short* qko = (short*)out0;
        short* vto = (short*)out1;
        if (n < 1024) {
          float bs = bq_[n];
#pragma unroll
          for (int r = 0; r < 4; ++r)
            qko[(long)(mB + r) * 2048 + n] = f2bf((acc[i][j][r] + bs) * QSCALE);
        } else if (n < 2048) {
          float bs = bk_[n - 1024];
#pragma unroll
          for (int r = 0; r < 4; ++r)
            qko[(long)(mB + r) * 2048 + n] = f2bf(acc[i][j][r] + bs);
        } else {
          float bs = bv_[n - 2048];
          short4 pk;
          pk.x = f2bf(acc[i][j][0] + bs);
          pk.y = f2bf(acc[i][j][1] + bs);
          pk.z = f2bf(acc[i][j][2] + bs);
          pk.w = f2bf(acc[i][j][3] + bs);
          *(short4*)(vto + (long)(n - 2048) * S_ + mB) = pk;
        }
      }
    }
  }
}

// ---- flash attention, swapped-operand: grid (S/128, H), 4 waves x 32 q-rows.
// S' = mfma(K,Q): lane holds q = lane&15, kv = 16*kc + 4*(lane>>4) + r  -> softmax
// is reg-local (15 fmax) + 2 shfl_xor. P -> per-wave LDS [q][kv] -> ds_read_b128
// B-frags. PV: O^T = mfma(V^T, P). Defer-max (THR=8, log2 domain), reg-dbuf K,
// V prefetch under softmax, setprio on MFMA clusters.
__global__ __launch_bounds__(256, 2)
void attn_kernel(const short* __restrict__ qk, const short* __restrict__ vT,
                 short* __restrict__ attnH, short* __restrict__ attnL) {
  __shared__ short plds[4][32][72];  // per-wave P tile, stride 144B
  const int qt = blockIdx.x, h = blockIdx.y;
  const int tid = threadIdx.x;
  const int wave = tid >> 6, lane = tid & 63;
  const int lg = lane >> 4, lr = lane & 15;
  const int qrow0 = qt * 128 + wave * 32;

  const short* qh = qk + (long)qrow0 * 2048 + h * 64;
  const short* kh = qk + 1024 + h * 64;
  const short* vh = vT + (long)h * 64 * S_;

  // Q as B-operand frags: Q[qb*16+lr][di*32 + lg*8 + j]
  bf16x8_t qf[2][2];
#pragma unroll
  for (int qb = 0; qb < 2; ++qb)
#pragma unroll
    for (int di = 0; di < 2; ++di)
      qf[qb][di] = *(const bf16x8_t*)(qh + (long)(qb * 16 + lr) * 2048 + di * 32 + lg * 8);

  float m[2] = {-1e30f, -1e30f}, l[2] = {0.f, 0.f};
  f32x4_t o[2][4];
#pragma unroll
  for (int qb = 0; qb < 2; ++qb)
#pragma unroll
    for (int dd = 0; dd < 4; ++dd) o[qb][dd] = (f32x4_t){0.f, 0.f, 0.f, 0.f};

  auto loadK = [&](bf16x8_t (&kf)[8], int kt) {
    const short* kb = kh + (long)kt * 64 * 2048;
#pragma unroll
    for (int kc = 0; kc < 4; ++kc)
#pragma unroll
      for (int di = 0; di < 2; ++di)
        kf[kc * 2 + di] =
            *(const bf16x8_t*)(kb + (long)(kc * 16 + lr) * 2048 + di * 32 + lg * 8);
  };

  auto step = [&](int kt, bf16x8_t (&kf)[8], bf16x8_t (&kn)[8]) {
    // V prefetch (used after softmax)
    bf16x8_t vf[8];
#pragma unroll
    for (int dd = 0; dd < 4; ++dd)
#pragma unroll
      for (int ks = 0; ks < 2; ++ks)
        vf[dd * 2 + ks] = *(const bf16x8_t*)(vh + (long)(dd * 16 + lr) * S_ +
                                             kt * 64 + ks * 32 + lg * 8);
    // S' = K.Q (swapped): 16 MFMA
    f32x4_t sacc[2][4];
#pragma unroll
    for (int qb = 0; qb < 2; ++qb)
#pragma unroll
      for (int kc = 0; kc < 4; ++kc) sacc[qb][kc] = (f32x4_t){0.f, 0.f, 0.f, 0.f};
    __builtin_amdgcn_s_setprio(1);
#pragma unroll
    for (int kc = 0; kc < 4; ++kc)
#pragma unroll
      for (int qb = 0; qb < 2; ++qb) {
        sacc[qb][kc] = MFMA16(kf[kc * 2 + 0], qf[qb][0], sacc[qb][kc]);
        sacc[qb][kc] = MFMA16(kf[kc * 2 + 1], qf[qb][1], sacc[qb][kc]);
      }
    __builtin_amdgcn_s_setprio(0);
    // prefetch next K tile (latency hidden under softmax + P-LDS)
    if (kt + 1 < S_ / 64) loadK(kn, kt + 1);

    // softmax (per lane: one q-column, 16 kv values per qb)
#pragma unroll
    for (int qb = 0; qb < 2; ++qb) {
      float p01 = fmaxf(fmaxf(sacc[qb][0][0], sacc[qb][0][1]),
                        fmaxf(sacc[qb][0][2], sacc[qb][0][3]));
      float p23 = fmaxf(fmaxf(sacc[qb][1][0], sacc[qb][1][1]),
                        fmaxf(sacc[qb][1][2], sacc[qb][1][3]));
      float p45 = fmaxf(fmaxf(sacc[qb][2][0], sacc[qb][2][1]),
                        fmaxf(sacc[qb][2][2], sacc[qb][2][3]));
      float p67 = fmaxf(fmaxf(sacc[qb][3][0], sacc[qb][3][1]),
                        fmaxf(sacc[qb][3][2], sacc[qb][3][3]));
      float pmax = fmaxf(fmaxf(p01, p23), fmaxf(p45, p67));
      pmax = fmaxf(pmax, __shfl_xor(pmax, 16));
      pmax = fmaxf(pmax, __shfl_xor(pmax, 32));
      if (!__all(pmax <= m[qb] + 8.0f)) {  // defer-max: rescale rarely fires
        float ef = exp2f(m[qb] - pmax);
        m[qb] = pmax;
        l[qb] *= ef;
#pragma unroll
        for (int dd = 0; dd < 4; ++dd) o[qb][dd] *= ef;
      }
      float mq = m[qb];
      float rsum = 0.f;
#pragma unroll
      for (int kc = 0; kc < 4; ++kc) {
        float e0 = exp2f(sacc[qb][kc][0] - mq);
        float e1 = exp2f(sacc[qb][kc][1] - mq);
        float e2 = exp2f(sacc[qb][kc][2] - mq);
        float e3 = exp2f(sacc[qb][kc][3] - mq);
        rsum += (e0 + e1) + (e2 + e3);
        uint2 w;
        w.x = cvtpk_bf16(e0, e1);
        w.y = cvtpk_bf16(e2, e3);
        *(uint2*)&plds[wave][qb * 16 + lr][kc * 16 + lg * 4] = w;
      }
      rsum += __shfl_xor(rsum, 16);
      rsum += __shfl_xor(rsum, 32);
      l[qb] += rsum;
    }
    // P back as B-frags: P^T rows q=lr, kv contiguous
    bf16x8_t pb[2][2];
#pragma unroll
    for (int qb = 0; qb < 2; ++qb)
#pragma unroll
      for (int ks = 0; ks < 2; ++ks)
        pb[qb][ks] = *(const bf16x8_t*)&plds[wave][qb * 16 + lr][ks * 32 + lg * 8];
    // O^T += V^T . P : 16 MFMA
    __builtin_amdgcn_s_setprio(1);
#pragma unroll
    for (int dd = 0; dd < 4; ++dd)
#pragma unroll
      for (int qb = 0; qb < 2; ++qb) {
        o[qb][dd] = MFMA16(vf[dd * 2 + 0], pb[qb][0], o[qb][dd]);
        o[qb][dd] = MFMA16(vf[dd * 2 + 1], pb[qb][1], o[qb][dd]);
      }
    __builtin_amdgcn_s_setprio(0);
  };

  bf16x8_t k0f[8], k1f[8];
  loadK(k0f, 0);
  for (int kt = 0; kt < S_ / 64; kt += 2) {
    step(kt, k0f, k1f);
    step(kt + 1, k1f, k0f);
  }

  // normalize + store hi/lo (O^T: lane has 4 consecutive d per (qb,dd))
#pragma unroll
  for (int qb = 0; qb < 2; ++qb) {
    float inv = 1.0f / l[qb];
    int q = qrow0 + qb * 16 + lr;
#pragma unroll
    for (int dd = 0; dd < 4; ++dd) {
      long base = (long)q * D_ + h * 64 + dd * 16 + lg * 4;
      short4 hh, ll;
      float v0 = o[qb][dd][0] * inv; hh.x = f2bf(v0); ll.x = f2bf(v0 - bf2f(hh.x));
      float v1 = o[qb][dd][1] * inv; hh.y = f2bf(v1); ll.y = f2bf(v1 - bf2f(hh.y));
      float v2 = o[qb][dd][2] * inv; hh.z = f2bf(v2); ll.z = f2bf(v2 - bf2f(hh.z));
      float v3 = o[qb][dd][3] * inv; hh.w = f2bf(v3); ll.w = f2bf(v3 - bf2f(hh.w));
      *(short4*)(attnH + base) = hh;
      *(short4*)(attnL + base) = ll;
    }
  }
}

// ---- fused: x = pA + pB + res + bias; LayerNorm; optional hi/lo bf16 outputs
template<int WHL>
__global__ __launch_bounds__(256)
void ln_fused(const float* __restrict__ pA, const float* __restrict__ pB,
              const float* __restrict__ res, const float* __restrict__ bias,
              const float* __restrict__ g, const float* __restrict__ b,
              float* __restrict__ outF, short* __restrict__ outH,
              short* __restrict__ outL) {
  __shared__ float red[8];
  const int row = blockIdx.x, tid = threadIdx.x;
  const long base = (long)row * D_ + tid * 4;
  float4 a = *(const float4*)(pA + base);
  float4 c = *(const float4*)(pB + base);
  float4 rr = *(const float4*)(res + base);
  float4 bb = *(const float4*)(bias + tid * 4);
  float x0 = a.x + c.x + rr.x + bb.x;
  float x1v = a.y + c.y + rr.y + bb.y;
  float x2v = a.z + c.z + rr.z + bb.z;
  float x3v = a.w + c.w + rr.w + bb.w;
  float s = x0 + x1v + x2v + x3v;
  float s2 = x0 * x0 + x1v * x1v + x2v * x2v + x3v * x3v;
#pragma unroll
  for (int m = 1; m < 64; m <<= 1) {
    s += __shfl_xor(s, m);
    s2 += __shfl_xor(s2, m);
  }
  int wave = tid >> 6, lane = tid & 63;
  if (lane == 0) { red[wave * 2] = s; red[wave * 2 + 1] = s2; }
  __syncthreads();
  s = red[0] + red[2] + red[4] + red[6];
  s2 = red[1] + red[3] + red[5] + red[7];
  float mu = s * (1.f / D_);
  float var = s2 * (1.f / D_) - mu * mu;
  float rs = rsqrtf(var + 1e-5f);
  float4 gv = *(const float4*)(g + tid * 4);
  float4 bv = *(const float4*)(b + tid * 4);
  float y0 = (x0 - mu) * rs * gv.x + bv.x;
  float y1 = (x1v - mu) * rs * gv.y + bv.y;
  float y2 = (x2v - mu) * rs * gv.z + bv.z;
  float y3 = (x3v - mu) * rs * gv.w + bv.w;
  float4 ov = {y0, y1, y2, y3};
  *(float4*)(outF + base) = ov;
  if constexpr (WHL) {
    short4 hh, ll;
    hh.x = f2bf(y0); ll.x = f2bf(y0 - bf2f(hh.x));
    hh.y = f2bf(y1); ll.y = f2bf(y1 - bf2f(hh.y));
    hh.z = f2bf(y2); ll.z = f2bf(y2 - bf2f(hh.z));
    hh.w = f2bf(y3); ll.w = f2bf(y3 - bf2f(hh.w));
    *(short4*)(outH + base) = hh;
    *(short4*)(outL + base) = ll;
  }
}

extern "C" void kernel_launch(void* const* d_in, const int* in_sizes, int n_in,
                              void* d_out, int out_size, void* d_ws, size_t ws_size,
                              hipStream_t stream) {
  const float* src  = (const float*)d_in[0];
  const float* Wq   = (const float*)d_in[1];
  const float* bq   = (const float*)d_in[2];
  const float* Wk   = (const float*)d_in[3];
  const float* bk   = (const float*)d_in[4];
  const float* Wv   = (const float*)d_in[5];
  const float* bv   = (const float*)d_in[6];
  const float* Wo   = (const float*)d_in[7];
  const float* bo   = (const float*)d_in[8];
  const float* ln1g = (const float*)d_in[9];
  const float* ln1b = (const float*)d_in[10];
  const float* W1   = (const float*)d_in[11];
  const float* b1   = (const float*)d_in[12];
  const float* W2   = (const float*)d_in[13];
  const float* b2   = (const float*)d_in[14];
  const float* ln2g = (const float*)d_in[15];
  const float* ln2b = (const float*)d_in[16];
  float* out = (float*)d_out;

  const size_t SD = (size_t)S_ * D_;
  const size_t SF = (size_t)S_ * F_;

  char* w = (char*)d_ws;
  auto take = [&](size_t bytes) {
    char* p = w;
    w += (bytes + 255) & ~(size_t)255;
    return p;
  };
  // region A (aliased by W2 partials after attention is done):
  short* srcH  = (short*)take(SD * 2);
  short* srcL  = (short*)take(SD * 2);
  short* qkb   = (short*)take((size_t)S_ * 2048 * 2);
  short* vTb   = (short*)take((size_t)D_ * S_ * 2);
  // region B (aliased by Wo partials before W1 writes h1):
  short* h1H   = (short*)take(SF * 2);
  short* h1L   = (short*)take(SF * 2);
  // weights
  short* wqkvH = (short*)take((size_t)3072 * D_ * 2);
  short* wqkvL = (short*)take((size_t)3072 * D_ * 2);
  short* woH   = (short*)take((size_t)D_ * D_ * 2);
  short* woL   = (short*)take((size_t)D_ * D_ * 2);
  short* w1H   = (short*)take((size_t)F_ * D_ * 2);
  short* w1L   = (short*)take((size_t)F_ * D_ * 2);
  short* w2H   = (short*)take((size_t)D_ * F_ * 2);
  short* w2L   = (short*)take((size_t)D_ * F_ * 2);
  // activations
  short* attnH = (short*)take(SD * 2);
  short* attnL = (short*)take(SD * 2);
  float* x1    = (float*)take(SD * 4);
  short* x1H   = (short*)take(SD * 2);
  short* x1L   = (short*)take(SD * 2);

  float* partWo = (float*)h1H;   // 2*SD fp32 = 33.5 MB, fits in h1H (SF*2)
  float* partW2 = (float*)srcH;  // 2*SD fp32 spans srcH+srcL+qkb, all dead by then

  dim3 blk(256);

  // weight prep (transpose + hi/lo split); QKV into one [3072][1024] buffer
  prep_w<1><<<dim3(32, 32), blk, 0, stream>>>(Wq, wqkvH, wqkvL, D_, D_);
  prep_w<1><<<dim3(32, 32), blk, 0, stream>>>(Wk, wqkvH + (size_t)1024 * D_,
                                              wqkvL + (size_t)1024 * D_, D_, D_);
  prep_w<1><<<dim3(32, 32), blk, 0, stream>>>(Wv, wqkvH + (size_t)2048 * D_,
                                              wqkvL + (size_t)2048 * D_, D_, D_);
  prep_w<0><<<dim3(32, 32), blk, 0, stream>>>(Wo, woH, woL, D_, D_);
  prep_w<0><<<dim3(128, 32), blk, 0, stream>>>(W1, w1H, w1L, D_, F_);
  prep_w<0><<<dim3(32, 128), blk, 0, stream>>>(W2, w2H, w2L, F_, D_);

  // src -> hi/lo
  cvt_hl<<<dim3(4096), blk, 0, stream>>>(src, srcH, srcL);

  // fused QKV projection (q pre-scaled by QSCALE, v transposed per head)
  gemm_bf3<EPI_QKV, 1><<<dim3(32, 24), blk, 0, stream>>>(
      srcH, srcL, wqkvH, wqkvL, D_, S_, 3072, bq, bk, bv, qkb, vTb);

  // flash attention -> attn hi/lo [S][1024]
  attn_kernel<<<dim3(32, 16), blk, 0, stream>>>(qkb, vTb, attnH, attnL);

  // Wo projection, split-K=2 partials; LN1 fuses partials + src + bo
  gemm_bf3<EPI_PART, 2><<<dim3(32, 8, 2), blk, 0, stream>>>(
      attnH, attnL, woH, woL, D_, S_, D_, nullptr, nullptr, nullptr, partWo, nullptr);
  ln_fused<1><<<dim3(S_), blk, 0, stream>>>(partWo, partWo + SD, src, bo,
                                            ln1g, ln1b, x1, x1H, x1L);

  // FFN
  gemm_bf3<EPI_RELUHL, 1><<<dim3(32, 32), blk, 0, stream>>>(
      x1H, x1L, w1H, w1L, D_, S_, F_, b1, nullptr, nullptr, h1H, h1L);
  gemm_bf3<EPI_PART, 2><<<dim3(32, 8, 2), blk, 0, stream>>>(
      h1H, h1L, w2H, w2L, F_, S_, D_, nullptr, nullptr, nullptr, partW2, nullptr);
  ln_fused<0><<<dim3(S_), blk, 0, stream>>>(partW2, partW2 + SD, x1, b2,
                                            ln2g, ln2b, out, nullptr, nullptr);

  (void)in_sizes; (void)n_in; (void)out_size; (void)ws_size;
}